// Round 20
// baseline (200.814 us; speedup 1.0000x reference)
//
#include <hip/hip_runtime.h>
#include <hip/hip_bf16.h>
#include <stdint.h>

typedef unsigned short u16;
typedef __bf16 bf16x8 __attribute__((ext_vector_type(8)));
typedef float f32x4 __attribute__((ext_vector_type(4)));

#define D_DIM 1024
#define B_ROWS 16384
#define M_ROWS 32768          // 2*B
#define BM 128
#define BN 128
#define BK 64

// ---------- bf16 bit helpers ----------
__device__ __forceinline__ u16 f2bs(float f) {
    union { float f; unsigned u; } v; v.f = f;
    unsigned r = v.u + 0x7FFFu + ((v.u >> 16) & 1u);   // RNE
    return (u16)(r >> 16);
}
__device__ __forceinline__ float bs2f(unsigned bits16) {
    union { unsigned u; float f; } v; v.u = bits16 << 16;
    return v.f;
}
__device__ __forceinline__ float b8x(uint4 q, int e) {
    unsigned w[4] = {q.x, q.y, q.z, q.w};
    return bs2f((w[e >> 1] >> ((unsigned)(e & 1) * 16u)) & 0xFFFFu);
}
__device__ __forceinline__ uint2 pack4(float4 f) {
    uint2 r;
    r.x = (unsigned)f2bs(f.x) | ((unsigned)f2bs(f.y) << 16);
    r.y = (unsigned)f2bs(f.z) | ((unsigned)f2bs(f.w) << 16);
    return r;
}

#define GLD16(gsrc, ldst)                                                      \
    __builtin_amdgcn_global_load_lds(                                          \
        (const __attribute__((address_space(1))) void*)(gsrc),                 \
        (__attribute__((address_space(3))) void*)(ldst), 16, 0, 0)

#define MFMA16(a, b, c) __builtin_amdgcn_mfma_f32_16x16x32_bf16((a), (b), (c), 0, 0, 0)

// ============================================================================
// prep_all: single dispatch, independent jobs by blockIdx range.
// ============================================================================
__global__ __launch_bounds__(256) void prep_all(const float* __restrict__ f1,
                                                const float* __restrict__ f2,
                                                const float* __restrict__ Wq,
                                                const float* __restrict__ Wk,
                                                const float* __restrict__ Wv,
                                                const float* __restrict__ bq,
                                                const float* __restrict__ bk,
                                                u16* __restrict__ X,
                                                u16* __restrict__ WqT,
                                                u16* __restrict__ WkT,
                                                u16* __restrict__ Wvb,
                                                float* __restrict__ u,
                                                float* __restrict__ v,
                                                float* __restrict__ cbuf) {
    const int bid = blockIdx.x;
    if (bid < 2048) {
        const float* in = (bid < 1024) ? Wq : Wk;
        u16* out = (bid < 1024) ? WqT : WkT;
        const int b = bid & 1023;
        __shared__ float lds[32][33];
        const int tx = threadIdx.x & 31;
        const int ty = threadIdx.x >> 5;
        const int r0 = (b >> 5) * 32;
        const int c0 = (b & 31) * 32;
#pragma unroll
        for (int i = 0; i < 4; ++i) {
            int r = ty + i * 8;
            lds[r][tx] = in[(size_t)(r0 + r) * D_DIM + c0 + tx];
        }
        __syncthreads();
#pragma unroll
        for (int i = 0; i < 4; ++i) {
            int r = ty + i * 8;
            out[(size_t)(c0 + r) * D_DIM + r0 + tx] = f2bs(lds[tx][r]);
        }
    } else if (bid < 3072) {
        size_t base = ((size_t)(bid - 2048) * 256 + threadIdx.x) * 4;
        *(uint2*)(Wvb + base) = pack4(*(const float4*)(Wv + base));
    } else if (bid < 3104) {
        const int b = bid - 3072;
        const int dl = threadIdx.x & 31;
        const int fg = threadIdx.x >> 5;
        const int d  = b * 32 + dl;
        float au = 0.f, av = 0.f;
        const int f0 = fg * 128;
        for (int f = f0; f < f0 + 128; ++f) {
            au = fmaf(Wq[(size_t)f * D_DIM + d], bk[f], au);
            av = fmaf(Wk[(size_t)f * D_DIM + d], bq[f], av);
        }
        __shared__ float su[8][32], sv[8][32];
        su[fg][dl] = au; sv[fg][dl] = av;
        __syncthreads();
        if (fg == 0) {
            float a = 0.f, b2 = 0.f;
#pragma unroll
            for (int g = 0; g < 8; ++g) { a += su[g][dl]; b2 += sv[g][dl]; }
            u[d] = a; v[d] = b2;
        }
        if (b == 0) {
            __shared__ float red[256];
            float p = 0.f;
            for (int f = threadIdx.x; f < D_DIM; f += 256) p = fmaf(bq[f], bk[f], p);
            red[threadIdx.x] = p;
            __syncthreads();
            for (int s = 128; s; s >>= 1) {
                if (threadIdx.x < s) red[threadIdx.x] += red[threadIdx.x + s];
                __syncthreads();
            }
            if (threadIdx.x == 0) cbuf[0] = red[0];
        }
    } else if (bid < 11296) {
        size_t idx  = (size_t)(bid - 3104) * 256 + threadIdx.x;
        size_t base = idx * 8;
        size_t brow = base >> 10;
        size_t col  = base & 1023;
        float4 a = *(const float4*)(f1 + base);
        float4 b = *(const float4*)(f1 + base + 4);
        uint2 p0 = pack4(a), p1 = pack4(b);
        uint4 o; o.x = p0.x; o.y = p0.y; o.z = p1.x; o.w = p1.y;
        *(uint4*)(X + (2 * brow) * D_DIM + col) = o;
    } else {
        size_t idx  = (size_t)(bid - 11296) * 256 + threadIdx.x;
        size_t base = idx * 8;
        size_t brow = base >> 10;
        size_t col  = base & 1023;
        float4 a = *(const float4*)(f2 + base);
        float4 b = *(const float4*)(f2 + base + 4);
        uint2 p0 = pack4(a), p1 = pack4(b);
        uint4 o; o.x = p0.x; o.y = p0.y; o.z = p1.x; o.w = p1.y;
        *(uint4*)(X + (2 * brow + 1) * D_DIM + col) = o;
    }
}

// ---------- small GEMM (round-5 proven 128x128 single-buffer): bf16 out ----------
__global__ __launch_bounds__(256, 3) void gemm_small(const u16* __restrict__ A,
                                                     const u16* __restrict__ W,
                                                     u16* __restrict__ C, int ncols) {
    constexpr int K = D_DIM;
    __shared__ u16 As[BM * BK];
    __shared__ u16 Bs[BN * BK];

    const int cpx  = gridDim.x >> 3;
    const int orig = (blockIdx.x & 7) * cpx + (blockIdx.x >> 3);
    const int nTn = ncols / BN;
    const int m0 = (orig / nTn) * BM, n0 = (orig % nTn) * BN;

    const int tid  = threadIdx.x;
    const int lane = tid & 63;
    const int wave = tid >> 6;
    const int wr = wave >> 1, wc = wave & 1;
    const int lr = lane & 15;
    const int kg = lane >> 4;

    f32x4 acc[4][4] = {};

    const int sr  = tid >> 3;
    const int scs = ((tid & 7) ^ ((tid >> 3) & 7)) * 8;
    const u16* aRow = A + (size_t)(m0 + sr) * K + scs;
    const u16* bRow = W + (size_t)(n0 + sr) * K + scs;
    u16* aDst = As + tid * 8;
    u16* bDst = Bs + tid * 8;

    for (int kt = 0; kt < K; kt += BK) {
#pragma unroll
        for (int i = 0; i < 4; ++i) {
            GLD16(aRow + (size_t)i * 32 * K + kt, aDst + i * 2048);
            GLD16(bRow + (size_t)i * 32 * K + kt, bDst + i * 2048);
        }
        __syncthreads();
#pragma unroll
        for (int kk = 0; kk < 2; ++kk) {
            bf16x8 af[4], bfr[4];
            const int kx = kk * 4 + kg;
#pragma unroll
            for (int mf = 0; mf < 4; ++mf) {
                const int R = wr * 64 + mf * 16 + lr;
                af[mf] = *(const bf16x8*)(As + R * 64 + ((kx ^ (R & 7)) * 8));
            }
#pragma unroll
            for (int nf = 0; nf < 4; ++nf) {
                const int S = wc * 64 + nf * 16 + lr;
                bfr[nf] = *(const bf16x8*)(Bs + S * 64 + ((kx ^ (S & 7)) * 8));
            }
#pragma unroll
            for (int mf = 0; mf < 4; ++mf)
#pragma unroll
                for (int nf = 0; nf < 4; ++nf)
                    acc[mf][nf] = MFMA16(af[mf], bfr[nf], acc[mf][nf]);
        }
        __syncthreads();
    }

    const int cr = (lane >> 4) * 4;
    const int cc = lane & 15;
#pragma unroll
    for (int mf = 0; mf < 4; ++mf)
#pragma unroll
        for (int nf = 0; nf < 4; ++nf) {
            int col = n0 + wc * 64 + nf * 16 + cc;
#pragma unroll
            for (int j = 0; j < 4; ++j) {
                int row = m0 + wr * 64 + mf * 16 + cr + j;
                C[(size_t)row * ncols + col] = f2bs(acc[mf][nf][j]);
            }
        }
}

// ============================================================================
// 8-phase 256x256 GEMM (round-7/8 verified), bf16 out — G = X @ M^T.
// ============================================================================
__global__ __launch_bounds__(512, 2) void gemm8p(const u16* __restrict__ A,
                                                 const u16* __restrict__ W,
                                                 u16* __restrict__ C,
                                                 int ncols) {
    constexpr int K  = D_DIM;
    constexpr int NT = K / 64;          // 16
    __shared__ u16 L[65536];

    const int cpx  = gridDim.x >> 3;
    const int orig = (blockIdx.x & 7) * cpx + (blockIdx.x >> 3);
    const int nTn  = ncols >> 8;
    const int m0 = (orig / nTn) << 8, n0 = (orig % nTn) << 8;

    const int tid  = threadIdx.x;
    const int lane = tid & 63;
    const int wid  = tid >> 6;
    const int wm = wid >> 2, wn = wid & 3;
    const int lr = lane & 15;
    const int kg = lane >> 4;
    const int r7 = lr & 7;
    const int cx0 = ((0 + kg) ^ r7) * 8;
    const int cx1 = ((4 + kg) ^ r7) * 8;
    const int sS  = (wn & 1) * 64;

    const int rb  = tid >> 3;
    const int scs = ((tid & 7) ^ (rb & 7)) * 8;
    const u16* aB = A + (size_t)(m0 + rb) * K + scs;
    const u16* bB = W + (size_t)(n0 + rb) * K + scs;
    u16* aD = L + tid * 8;
    u16* bD = L + 32768 + tid * 8;

#define ST_HALF(tile, h)                                                       \
    {                                                                          \
        const int d_ = (tile) & 1;                                             \
        const size_t ko_ = (size_t)(tile) * 64;                                \
        if ((h) < 2) {                                                         \
            const u16* s_ = aB + (size_t)(h) * 128 * K + ko_;                  \
            u16* t_ = aD + (d_ * 2 + (h)) * 8192;                              \
            GLD16(s_, t_);                                                     \
            GLD16(s_ + (size_t)64 * K, t_ + 4096);                            \
        } else {                                                               \
            const u16* s_ = bB + (size_t)((h) - 2) * 128 * K + ko_;            \
            u16* t_ = bD + (d_ * 2 + ((h) - 2)) * 8192;                        \
            GLD16(s_, t_);                                                     \
            GLD16(s_ + (size_t)64 * K, t_ + 4096);                            \
        }                                                                      \
    }

    f32x4 acc[8][4] = {};
    bf16x8 af[8][2], bf[4][2];

#pragma unroll
    for (int h = 0; h < 4; ++h) ST_HALF(0, h);
#pragma unroll
    for (int h = 0; h < 4; ++h) ST_HALF(1, h);
    asm volatile("s_waitcnt vmcnt(8)" ::: "memory");
    __builtin_amdgcn_s_barrier();

#pragma unroll 2
    for (int t = 0; t < NT; ++t) {
        const int d = t & 1;
        const u16* Ab = L + (d * 2 + wm) * 8192;
        const u16* Bb = L + 32768 + (d * 2 + (wn >> 1)) * 8192;
        const bool more = (t + 2 < NT);

#pragma unroll
        for (int m = 0; m < 4; ++m) {
            const int R = m * 16 + lr;
            af[m][0] = *(const bf16x8*)(Ab + R * 64 + cx0);
            af[m][1] = *(const bf16x8*)(Ab + R * 64 + cx1);
        }
#pragma unroll
        for (int n = 0; n < 2; ++n) {
            const int S = sS + n * 16 + lr;
            bf[n][0] = *(const bf16x8*)(Bb + S * 64 + cx0);
            bf[n][1] = *(const bf16x8*)(Bb + S * 64 + cx1);
        }
        __builtin_amdgcn_s_barrier();
        __builtin_amdgcn_s_setprio(1);
#pragma unroll
        for (int m = 0; m < 4; ++m)
#pragma unroll
            for (int n = 0; n < 2; ++n) {
                acc[m][n] = MFMA16(af[m][0], bf[n][0], acc[m][n]);
                acc[m][n] = MFMA16(af[m][1], bf[n][1], acc[m][n]);
            }
        __builtin_amdgcn_s_setprio(0);
        __builtin_amdgcn_s_barrier();

#pragma unroll
        for (int n = 2; n < 4; ++n) {
            const int S = sS + n * 16 + lr;
            bf[n][0] = *(const bf16x8*)(Bb + S * 64 + cx0);
            bf[n][1] = *(const bf16x8*)(Bb + S * 64 + cx1);
        }
        __builtin_amdgcn_s_barrier();
        __builtin_amdgcn_s_setprio(1);
#pragma unroll
        for (int m = 0; m < 4; ++m)
#pragma unroll
            for (int n = 2; n < 4; ++n) {
                acc[m][n] = MFMA16(af[m][0], bf[n][0], acc[m][n]);
                acc[m][n] = MFMA16(af[m][1], bf[n][1], acc[m][n]);
            }
        __builtin_amdgcn_s_setprio(0);
        __builtin_amdgcn_s_barrier();

#pragma unroll
        for (int m = 4; m < 8; ++m) {
            const int R = m * 16 + lr;
            af[m][0] = *(const bf16x8*)(Ab + R * 64 + cx0);
            af[m][1] = *(const bf16x8*)(Ab + R * 64 + cx1);
        }
        if (more) { ST_HALF(t + 2, 2); ST_HALF(t + 2, 3); }
        __builtin_amdgcn_s_barrier();
        __builtin_amdgcn_s_setprio(1);
#pragma unroll
        for (int m = 4; m < 8; ++m)
#pragma unroll
            for (int n = 0; n < 2; ++n) {
                acc[m][n] = MFMA16(af[m][0], bf[n][0], acc[m][n]);
                acc[m][n] = MFMA16(af[m][1], bf[n][1], acc[m][n]);
            }
        __builtin_amdgcn_s_setprio(0);
        __builtin_amdgcn_s_barrier();

        if (more) { ST_HALF(t + 2, 0); ST_HALF(t + 2, 1); }
        __builtin_amdgcn_s_barrier();
        __builtin_amdgcn_s_setprio(1);
#pragma unroll
        for (int m = 4; m < 8; ++m)
#pragma unroll
            for (int n = 2; n < 4; ++n) {
                acc[m][n] = MFMA16(af[m][0], bf[n][0], acc[m][n]);
                acc[m][n] = MFMA16(af[m][1], bf[n][1], acc[m][n]);
            }
        __builtin_amdgcn_s_setprio(0);
        if (more) asm volatile("s_waitcnt vmcnt(8)" ::: "memory");
        else      asm volatile("s_waitcnt vmcnt(0)" ::: "memory");
        __builtin_amdgcn_s_barrier();
    }
#undef ST_HALF

    const int cr = (lane >> 4) * 4;
    const int cc = lane & 15;
#pragma unroll
    for (int mf = 0; mf < 8; ++mf)
#pragma unroll
        for (int nf = 0; nf < 4; ++nf) {
            int col = n0 + wn * 64 + nf * 16 + cc;
#pragma unroll
            for (int j = 0; j < 4; ++j) {
                int row = m0 + wm * 128 + mf * 16 + cr + j;
                C[(size_t)row * ncols + col] = f2bs(acc[mf][nf][j]);
            }
        }
}

// ============================================================================
// gemm_v2: V-GEMM on 256x128 tiles (2 rounds/CU — escapes the 1-round regime).
// Same 8-phase schedule, B-operand has 1 half (128 rows), 6 loads/K-tile,
// counted vmcnt(6). out = Z @ Wv^T + 2*bv (f32). LDS 96 KB.
// ============================================================================
__global__ __launch_bounds__(512, 2) void gemm_v2(const u16* __restrict__ A,
                                                  const u16* __restrict__ W,
                                                  const float* __restrict__ bias,
                                                  float* __restrict__ out) {
    constexpr int K  = D_DIM;
    constexpr int NT = K / 64;          // 16
    __shared__ u16 L[49152];            // A: [0,32768), B: [32768,49152)

    const int cpx  = gridDim.x >> 3;            // 512/8 = 64
    const int orig = (blockIdx.x & 7) * cpx + (blockIdx.x >> 3);
    const int nTn  = 8;                         // 1024/128
    const int m0 = (orig / nTn) * 256, n0 = (orig % nTn) * 128;

    const int tid  = threadIdx.x;
    const int lane = tid & 63;
    const int wid  = tid >> 6;                  // 0..7
    const int wm = wid >> 2, wn = wid & 3;      // 2 x 4; wave tile 128x32
    const int lr = lane & 15;
    const int kg = lane >> 4;
    const int r7 = lr & 7;
    const int cx0 = ((0 + kg) ^ r7) * 8;
    const int cx1 = ((4 + kg) ^ r7) * 8;
    const int sS  = wn * 32;                    // B row base for this wave

    const int rb  = tid >> 3;
    const int scs = ((tid & 7) ^ (rb & 7)) * 8;
    const u16* aB = A + (size_t)(m0 + rb) * K + scs;
    const u16* bB = W + (size_t)(n0 + rb) * K + scs;
    u16* aD = L + tid * 8;
    u16* bD = L + 32768 + tid * 8;

#define ST_V(tile, h)                                                          \
    {                                                                          \
        const int d_ = (tile) & 1;                                             \
        const size_t ko_ = (size_t)(tile) * 64;                                \
        if ((h) < 2) {                                                         \
            const u16* s_ = aB + (size_t)(h) * 128 * K + ko_;                  \
            u16* t_ = aD + (d_ * 2 + (h)) * 8192;                              \
            GLD16(s_, t_);                                                     \
            GLD16(s_ + (size_t)64 * K, t_ + 4096);                            \
        } else {                                                               \
            u16* t_ = bD + d_ * 8192;                                          \
            GLD16(bB + ko_, t_);                                               \
            GLD16(bB + (size_t)64 * K + ko_, t_ + 4096);                      \
        }                                                                      \
    }

    f32x4 acc[8][2] = {};
    bf16x8 af[8][2], bf[2][2];

#pragma unroll
    for (int h = 0; h < 3; ++h) ST_V(0, h);
#pragma unroll
    for (int h = 0; h < 3; ++h) ST_V(1, h);
    asm volatile("s_waitcnt vmcnt(6)" ::: "memory");
    __builtin_amdgcn_s_barrier();

#pragma unroll 2
    for (int t = 0; t < NT; ++t) {
        const int d = t & 1;
        const u16* Ab = L + (d * 2 + wm) * 8192;
        const u16* Bb = L + 32768 + d * 8192;
        const bool more = (t + 2 < NT);

        // ---- phase 0: read A m0-3 + B n0; MFMA m0-3 x n0
#pragma unroll
        for (int m = 0; m < 4; ++m) {
            const int R = m * 16 + lr;
            af[m][0] = *(const bf16x8*)(Ab + R * 64 + cx0);
            af[m][1] = *(const bf16x8*)(Ab + R * 64 + cx1);
        }
        {
            const int S = sS + lr;
            bf[0][0] = *(const bf16x8*)(Bb + S * 64 + ((kg ^ (S & 7)) * 8));
            bf[0][1] = *(const bf16x8*)(Bb + S * 64 + (((4 + kg) ^ (S & 7)) * 8));
        }
        __builtin_amdgcn_s_barrier();
        __builtin_amdgcn_s_setprio(1);
#pragma unroll
        for (int m = 0; m < 4; ++m) {
            acc[m][0] = MFMA16(af[m][0], bf[0][0], acc[m][0]);
            acc[m][0] = MFMA16(af[m][1], bf[0][1], acc[m][0]);
        }
        __builtin_amdgcn_s_setprio(0);
        __builtin_amdgcn_s_barrier();

        // ---- phase 1: read B n1; MFMA m0-3 x n1
        {
            const int S = sS + 16 + lr;
            bf[1][0] = *(const bf16x8*)(Bb + S * 64 + ((kg ^ (S & 7)) * 8));
            bf[1][1] = *(const bf16x8*)(Bb + S * 64 + (((4 + kg) ^ (S & 7)) * 8));
        }
        __builtin_amdgcn_s_barrier();
        __builtin_amdgcn_s_setprio(1);
#pragma unroll
        for (int m = 0; m < 4; ++m) {
            acc[m][1] = MFMA16(af[m][0], bf[1][0], acc[m][1]);
            acc[m][1] = MFMA16(af[m][1], bf[1][1], acc[m][1]);
        }
        __builtin_amdgcn_s_setprio(0);
        __builtin_amdgcn_s_barrier();

        // ---- phase 2: read A m4-7; stage B of t+2; MFMA m4-7 x n0
#pragma unroll
        for (int m = 4; m < 8; ++m) {
            const int R = m * 16 + lr;
            af[m][0] = *(const bf16x8*)(Ab + R * 64 + cx0);
            af[m][1] = *(const bf16x8*)(Ab + R * 64 + cx1);
        }
        if (more) { ST_V(t + 2, 2); }
        __builtin_amdgcn_s_barrier();
        __builtin_amdgcn_s_setprio(1);
#pragma unroll
        for (int m = 4; m < 8; ++m) {
            acc[m][0] = MFMA16(af[m][0], bf[0][0], acc[m][0]);
            acc[m][0] = MFMA16(af[m][1], bf[0][1], acc[m][0]);
        }
        __builtin_amdgcn_s_setprio(0);
        __builtin_amdgcn_s_barrier();

        // ---- phase 3: stage A of t+2; MFMA m4-7 x n1; counted vmcnt
        if (more) { ST_V(t + 2, 0); ST_V(t + 2, 1); }
        __builtin_amdgcn_s_barrier();
        __builtin_amdgcn_s_setprio(1);
#pragma unroll
        for (int m = 4; m < 8; ++m) {
            acc[m][1] = MFMA16(af[m][0], bf[1][0], acc[m][1]);
            acc[m][1] = MFMA16(af[m][1], bf[1][1], acc[m][1]);
        }
        __builtin_amdgcn_s_setprio(0);
        if (more) asm volatile("s_waitcnt vmcnt(6)" ::: "memory");
        else      asm volatile("s_waitcnt vmcnt(0)" ::: "memory");
        __builtin_amdgcn_s_barrier();
    }
#undef ST_V

    const int cr = (lane >> 4) * 4;
    const int cc = lane & 15;
#pragma unroll
    for (int mf = 0; mf < 8; ++mf)
#pragma unroll
        for (int nf = 0; nf < 2; ++nf) {
            int col = n0 + wn * 32 + nf * 16 + cc;
            float bsv = 2.0f * bias[col];
#pragma unroll
            for (int j = 0; j < 4; ++j) {
                int row = m0 + wm * 128 + mf * 16 + cr + j;
                out[(size_t)row * D_DIM + col] = acc[mf][nf][j] + bsv;
            }
        }
}

// ---------- scores + Z ----------
__global__ __launch_bounds__(256) void scores_z(const u16* __restrict__ X,
                                                const u16* __restrict__ G,
                                                const float* __restrict__ u,
                                                const float* __restrict__ v,
                                                const float* __restrict__ cbuf,
                                                u16* __restrict__ Z) {
    const int wave = threadIdx.x >> 6;
    const int lane = threadIdx.x & 63;
    const size_t b = (size_t)blockIdx.x * 4 + wave;
    const u16* x0p = X + (2 * b) * D_DIM;
    const u16* x1p = x0p + D_DIM;
    const u16* g0p = G + (2 * b) * D_DIM;
    const u16* g1p = g0p + D_DIM;

    float d00 = 0.f, d01 = 0.f, d10 = 0.f, d11 = 0.f;
    float au0 = 0.f, au1 = 0.f, bv0 = 0.f, bv1 = 0.f;
    uint4 x0c[2], x1c[2];
#pragma unroll
    for (int s = 0; s < 2; ++s) {
        const int c = s * 512 + lane * 8;
        x0c[s] = *(const uint4*)(x0p + c);
        x1c[s] = *(const uint4*)(x1p + c);
        uint4 g0 = *(const uint4*)(g0p + c);
        uint4 g1 = *(const uint4*)(g1p + c);
        float4 uuA = *(const float4*)(u + c);
        float4 uuB = *(const float4*)(u + c + 4);
        float4 vvA = *(const float4*)(v + c);
        float4 vvB = *(const float4*)(v + c + 4);
        float uA[8] = {uuA.x, uuA.y, uuA.z, uuA.w, uuB.x, uuB.y, uuB.z, uuB.w};
        float vA[8] = {vvA.x, vvA.y, vvA.z, vvA.w, vvB.x, vvB.y, vvB.z, vvB.w};
#pragma unroll
        for (int e = 0; e < 8; ++e) {
            float a0 = b8x(x0c[s], e), a1 = b8x(x1c[s], e);
            float c0 = b8x(g0, e),     c1 = b8x(g1, e);
            d00 = fmaf(a0, c0, d00); d01 = fmaf(a0, c1, d01);
            d10 = fmaf(a1, c0, d10); d11 = fmaf(a1, c1, d11);
            au0 = fmaf(uA[e], a0, au0); au1 = fmaf(uA[e], a1, au1);
            bv0 = fmaf(vA[e], a0, bv0); bv1 = fmaf(vA[e], a1, bv1);
        }
    }
#pragma unroll
    for (int off = 32; off; off >>= 1) {
        d00 += __shfl_xor(d00, off); d01 += __shfl_xor(d01, off);
        d10 += __shfl_xor(d10, off); d11 += __shfl_xor(d11, off);
        au0 += __shfl_xor(au0, off); au1 += __shfl_xor(au1, off);
        bv0 += __shfl_xor(bv0, off); bv1 += __shfl_xor(bv1, off);
    }
    const float cc0 = cbuf[0];
    const float sc = 1.0f / 32.0f;
    float s00 = (d00 + au0 + bv0 + cc0) * sc;
    float s01 = (d01 + au0 + bv1 + cc0) * sc;
    float s10 = (d10 + au1 + bv0 + cc0) * sc;
    float s11 = (d11 + au1 + bv1 + cc0) * sc;
    float mA = fmaxf(s00, s01);
    float e00 = expf(s00 - mA), e01 = expf(s01 - mA);
    float rA = 1.0f / (e00 + e01);
    float mB = fmaxf(s10, s11);
    float e10 = expf(s10 - mB), e11 = expf(s11 - mB);
    float rB = 1.0f / (e10 + e11);
    const float w0 = e00 * rA + e10 * rB;
    const float w1 = e01 * rA + e11 * rB;

#pragma unroll
    for (int s = 0; s < 2; ++s) {
        const int c = s * 512 + lane * 8;
        float4 lo, hi;
        lo.x = w0 * b8x(x0c[s], 0) + w1 * b8x(x1c[s], 0);
        lo.y = w0 * b8x(x0c[s], 1) + w1 * b8x(x1c[s], 1);
        lo.z = w0 * b8x(x0c[s], 2) + w1 * b8x(x1c[s], 2);
        lo.w = w0 * b8x(x0c[s], 3) + w1 * b8x(x1c[s], 3);
        hi.x = w0 * b8x(x0c[s], 4) + w1 * b8x(x1c[s], 4);
        hi.y = w0 * b8x(x0c[s], 5) + w1 * b8x(x1c[s], 5);
        hi.z = w0 * b8x(x0c[s], 6) + w1 * b8x(x1c[s], 6);
        hi.w = w0 * b8x(x0c[s], 7) + w1 * b8x(x1c[s], 7);
        uint2 pl = pack4(lo), ph = pack4(hi);
        uint4 o; o.x = pl.x; o.y = pl.y; o.z = ph.x; o.w = ph.y;
        *(uint4*)(Z + b * D_DIM + c) = o;
    }
}

extern "C" void kernel_launch(void* const* d_in, const int* in_sizes, int n_in,
                              void* d_out, int out_size, void* d_ws, size_t ws_size,
                              hipStream_t stream) {
    const float* f1 = (const float*)d_in[0];
    const float* f2 = (const float*)d_in[1];
    const float* Wq = (const float*)d_in[2];
    const float* bq = (const float*)d_in[3];
    const float* Wk = (const float*)d_in[4];
    const float* bk = (const float*)d_in[5];
    const float* Wv = (const float*)d_in[6];
    const float* bv = (const float*)d_in[7];
    float* out = (float*)d_out;

    char*   w    = (char*)d_ws;
    u16*    X    = (u16*)w;
    u16*    G    = X + (size_t)M_ROWS * D_DIM;
    u16*    Z    = G + (size_t)M_ROWS * D_DIM;
    u16*    Wvb  = Z + (size_t)B_ROWS * D_DIM;
    u16*    WqT  = Wvb + (size_t)D_DIM * D_DIM;
    u16*    WkT  = WqT + (size_t)D_DIM * D_DIM;
    u16*    Mb   = WkT + (size_t)D_DIM * D_DIM;
    float*  u    = (float*)(Mb + (size_t)D_DIM * D_DIM);
    float*  v    = u + D_DIM;
    float*  cbuf = v + D_DIM;

    prep_all<<<3104 + 2 * ((B_ROWS * D_DIM / 8) / 256), 256, 0, stream>>>(
        f1, f2, Wq, Wk, Wv, bq, bk, X, WqT, WkT, Wvb, u, v, cbuf);

    gemm_small<<<(D_DIM / BM) * (D_DIM / BN), 256, 0, stream>>>(WqT, WkT, Mb, D_DIM);
    gemm8p<<<(M_ROWS / 256) * (D_DIM / 256), 512, 0, stream>>>(X, Mb, G, D_DIM);
    scores_z<<<B_ROWS / 4, 256, 0, stream>>>(X, G, u, v, cbuf, Z);
    // V: 256x128 tiles, 512 blocks = 2 rounds/CU
    gemm_v2<<<(B_ROWS / 256) * (D_DIM / 128), 512, 0, stream>>>(Z, Wvb, bv, out);
}

// Round 21
// 194.500 us; speedup vs baseline: 1.0325x; 1.0325x over previous
//
#include <hip/hip_runtime.h>
#include <hip/hip_bf16.h>
#include <stdint.h>

typedef unsigned short u16;
typedef __bf16 bf16x8 __attribute__((ext_vector_type(8)));
typedef float f32x4 __attribute__((ext_vector_type(4)));
typedef unsigned u32x4 __attribute__((ext_vector_type(4)));

#define D_DIM 1024
#define B_ROWS 16384
#define M_ROWS 32768          // 2*B
#define BM 128
#define BN 128
#define BK 64

// ---------- bf16 bit helpers ----------
__device__ __forceinline__ u16 f2bs(float f) {
    union { float f; unsigned u; } v; v.f = f;
    unsigned r = v.u + 0x7FFFu + ((v.u >> 16) & 1u);   // RNE
    return (u16)(r >> 16);
}
__device__ __forceinline__ float bs2f(unsigned bits16) {
    union { unsigned u; float f; } v; v.u = bits16 << 16;
    return v.f;
}
__device__ __forceinline__ float b8x(uint4 q, int e) {
    unsigned w[4] = {q.x, q.y, q.z, q.w};
    return bs2f((w[e >> 1] >> ((unsigned)(e & 1) * 16u)) & 0xFFFFu);
}
__device__ __forceinline__ uint2 pack4(float4 f) {
    uint2 r;
    r.x = (unsigned)f2bs(f.x) | ((unsigned)f2bs(f.y) << 16);
    r.y = (unsigned)f2bs(f.z) | ((unsigned)f2bs(f.w) << 16);
    return r;
}

#define GLD16(gsrc, ldst)                                                      \
    __builtin_amdgcn_global_load_lds(                                          \
        (const __attribute__((address_space(1))) void*)(gsrc),                 \
        (__attribute__((address_space(3))) void*)(ldst), 16, 0, 0)

#define MFMA16(a, b, c) __builtin_amdgcn_mfma_f32_16x16x32_bf16((a), (b), (c), 0, 0, 0)

// ============================================================================
// prep_all: single dispatch, independent jobs by blockIdx range.
//   [0,1024)       : transpose Wq -> WqT (bf16)
//   [1024,2048)    : transpose Wk -> WkT (bf16)
//   [2048,3072)    : cvt Wv -> Wvb (bf16)
//   [3072,3104)    : uvc (u = Wq^T bk, v = Wk^T bq, c = bq.bk)
//   [3104,11296)   : cvt f1 -> X rows 2b   (8 elems/thread, uint4 store)
//   [11296,19488)  : cvt f2 -> X rows 2b+1 (8 elems/thread, uint4 store)
// ============================================================================
__global__ __launch_bounds__(256) void prep_all(const float* __restrict__ f1,
                                                const float* __restrict__ f2,
                                                const float* __restrict__ Wq,
                                                const float* __restrict__ Wk,
                                                const float* __restrict__ Wv,
                                                const float* __restrict__ bq,
                                                const float* __restrict__ bk,
                                                u16* __restrict__ X,
                                                u16* __restrict__ WqT,
                                                u16* __restrict__ WkT,
                                                u16* __restrict__ Wvb,
                                                float* __restrict__ u,
                                                float* __restrict__ v,
                                                float* __restrict__ cbuf) {
    const int bid = blockIdx.x;
    if (bid < 2048) {
        const float* in = (bid < 1024) ? Wq : Wk;
        u16* out = (bid < 1024) ? WqT : WkT;
        const int b = bid & 1023;
        __shared__ float lds[32][33];
        const int tx = threadIdx.x & 31;
        const int ty = threadIdx.x >> 5;
        const int r0 = (b >> 5) * 32;
        const int c0 = (b & 31) * 32;
#pragma unroll
        for (int i = 0; i < 4; ++i) {
            int r = ty + i * 8;
            lds[r][tx] = in[(size_t)(r0 + r) * D_DIM + c0 + tx];
        }
        __syncthreads();
#pragma unroll
        for (int i = 0; i < 4; ++i) {
            int r = ty + i * 8;
            out[(size_t)(c0 + r) * D_DIM + r0 + tx] = f2bs(lds[tx][r]);
        }
    } else if (bid < 3072) {
        size_t base = ((size_t)(bid - 2048) * 256 + threadIdx.x) * 4;
        *(uint2*)(Wvb + base) = pack4(*(const float4*)(Wv + base));
    } else if (bid < 3104) {
        const int b = bid - 3072;
        const int dl = threadIdx.x & 31;
        const int fg = threadIdx.x >> 5;
        const int d  = b * 32 + dl;
        float au = 0.f, av = 0.f;
        const int f0 = fg * 128;
        for (int f = f0; f < f0 + 128; ++f) {
            au = fmaf(Wq[(size_t)f * D_DIM + d], bk[f], au);
            av = fmaf(Wk[(size_t)f * D_DIM + d], bq[f], av);
        }
        __shared__ float su[8][32], sv[8][32];
        su[fg][dl] = au; sv[fg][dl] = av;
        __syncthreads();
        if (fg == 0) {
            float a = 0.f, b2 = 0.f;
#pragma unroll
            for (int g = 0; g < 8; ++g) { a += su[g][dl]; b2 += sv[g][dl]; }
            u[d] = a; v[d] = b2;
        }
        if (b == 0) {
            __shared__ float red[256];
            float p = 0.f;
            for (int f = threadIdx.x; f < D_DIM; f += 256) p = fmaf(bq[f], bk[f], p);
            red[threadIdx.x] = p;
            __syncthreads();
            for (int s = 128; s; s >>= 1) {
                if (threadIdx.x < s) red[threadIdx.x] += red[threadIdx.x + s];
                __syncthreads();
            }
            if (threadIdx.x == 0) cbuf[0] = red[0];
        }
    } else if (bid < 11296) {
        size_t idx  = (size_t)(bid - 3104) * 256 + threadIdx.x;
        size_t base = idx * 8;
        size_t brow = base >> 10;
        size_t col  = base & 1023;
        float4 a = *(const float4*)(f1 + base);
        float4 b = *(const float4*)(f1 + base + 4);
        uint2 p0 = pack4(a), p1 = pack4(b);
        uint4 o; o.x = p0.x; o.y = p0.y; o.z = p1.x; o.w = p1.y;
        *(uint4*)(X + (2 * brow) * D_DIM + col) = o;
    } else {
        size_t idx  = (size_t)(bid - 11296) * 256 + threadIdx.x;
        size_t base = idx * 8;
        size_t brow = base >> 10;
        size_t col  = base & 1023;
        float4 a = *(const float4*)(f2 + base);
        float4 b = *(const float4*)(f2 + base + 4);
        uint2 p0 = pack4(a), p1 = pack4(b);
        uint4 o; o.x = p0.x; o.y = p0.y; o.z = p1.x; o.w = p1.y;
        *(uint4*)(X + (2 * brow + 1) * D_DIM + col) = o;
    }
}

// ---------- small GEMM (round-5 proven 128x128 single-buffer): bf16 out ----------
__global__ __launch_bounds__(256, 3) void gemm_small(const u16* __restrict__ A,
                                                     const u16* __restrict__ W,
                                                     u16* __restrict__ C, int ncols) {
    constexpr int K = D_DIM;
    __shared__ u16 As[BM * BK];
    __shared__ u16 Bs[BN * BK];

    const int cpx  = gridDim.x >> 3;
    const int orig = (blockIdx.x & 7) * cpx + (blockIdx.x >> 3);
    const int nTn = ncols / BN;
    const int m0 = (orig / nTn) * BM, n0 = (orig % nTn) * BN;

    const int tid  = threadIdx.x;
    const int lane = tid & 63;
    const int wave = tid >> 6;
    const int wr = wave >> 1, wc = wave & 1;
    const int lr = lane & 15;
    const int kg = lane >> 4;

    f32x4 acc[4][4] = {};

    const int sr  = tid >> 3;
    const int scs = ((tid & 7) ^ ((tid >> 3) & 7)) * 8;
    const u16* aRow = A + (size_t)(m0 + sr) * K + scs;
    const u16* bRow = W + (size_t)(n0 + sr) * K + scs;
    u16* aDst = As + tid * 8;
    u16* bDst = Bs + tid * 8;

    for (int kt = 0; kt < K; kt += BK) {
#pragma unroll
        for (int i = 0; i < 4; ++i) {
            GLD16(aRow + (size_t)i * 32 * K + kt, aDst + i * 2048);
            GLD16(bRow + (size_t)i * 32 * K + kt, bDst + i * 2048);
        }
        __syncthreads();
#pragma unroll
        for (int kk = 0; kk < 2; ++kk) {
            bf16x8 af[4], bfr[4];
            const int kx = kk * 4 + kg;
#pragma unroll
            for (int mf = 0; mf < 4; ++mf) {
                const int R = wr * 64 + mf * 16 + lr;
                af[mf] = *(const bf16x8*)(As + R * 64 + ((kx ^ (R & 7)) * 8));
            }
#pragma unroll
            for (int nf = 0; nf < 4; ++nf) {
                const int S = wc * 64 + nf * 16 + lr;
                bfr[nf] = *(const bf16x8*)(Bs + S * 64 + ((kx ^ (S & 7)) * 8));
            }
#pragma unroll
            for (int mf = 0; mf < 4; ++mf)
#pragma unroll
                for (int nf = 0; nf < 4; ++nf)
                    acc[mf][nf] = MFMA16(af[mf], bfr[nf], acc[mf][nf]);
        }
        __syncthreads();
    }

    const int cr = (lane >> 4) * 4;
    const int cc = lane & 15;
#pragma unroll
    for (int mf = 0; mf < 4; ++mf)
#pragma unroll
        for (int nf = 0; nf < 4; ++nf) {
            int col = n0 + wc * 64 + nf * 16 + cc;
#pragma unroll
            for (int j = 0; j < 4; ++j) {
                int row = m0 + wr * 64 + mf * 16 + cr + j;
                C[(size_t)row * ncols + col] = f2bs(acc[mf][nf][j]);
            }
        }
}

// ============================================================================
// 8-phase 256x256 GEMM (round-7/8 verified K-loop), plain coalescable stores.
// MODE 0: bf16 C out (G-GEMM).  MODE 1: f32 out = acc + 2*bias (V-GEMM on Z).
// ============================================================================
template<int MODE>
__global__ __launch_bounds__(512, 2) void gemm8p(const u16* __restrict__ A,
                                                 const u16* __restrict__ W,
                                                 const float* __restrict__ bias,
                                                 u16* __restrict__ C,
                                                 float* __restrict__ out,
                                                 int ncols) {
    constexpr int K  = D_DIM;
    constexpr int NT = K / 64;          // 16
    __shared__ u16 L[65536];            // A: [0,32768), B: [32768,65536)

    const int cpx  = gridDim.x >> 3;
    const int orig = (blockIdx.x & 7) * cpx + (blockIdx.x >> 3);
    const int nTn  = ncols >> 8;
    const int m0 = (orig / nTn) << 8, n0 = (orig % nTn) << 8;

    const int tid  = threadIdx.x;
    const int lane = tid & 63;
    const int wid  = tid >> 6;          // 0..7
    const int wm = wid >> 2, wn = wid & 3;
    const int lr = lane & 15;
    const int kg = lane >> 4;
    const int r7 = lr & 7;
    const int cx0 = ((0 + kg) ^ r7) * 8;
    const int cx1 = ((4 + kg) ^ r7) * 8;
    const int sS  = (wn & 1) * 64;

    const int rb  = tid >> 3;
    const int scs = ((tid & 7) ^ (rb & 7)) * 8;
    const u16* aB = A + (size_t)(m0 + rb) * K + scs;
    const u16* bB = W + (size_t)(n0 + rb) * K + scs;
    u16* aD = L + tid * 8;
    u16* bD = L + 32768 + tid * 8;

#define ST_HALF(tile, h)                                                       \
    {                                                                          \
        const int d_ = (tile) & 1;                                             \
        const size_t ko_ = (size_t)(tile) * 64;                                \
        if ((h) < 2) {                                                         \
            const u16* s_ = aB + (size_t)(h) * 128 * K + ko_;                  \
            u16* t_ = aD + (d_ * 2 + (h)) * 8192;                              \
            GLD16(s_, t_);                                                     \
            GLD16(s_ + (size_t)64 * K, t_ + 4096);                            \
        } else {                                                               \
            const u16* s_ = bB + (size_t)((h) - 2) * 128 * K + ko_;            \
            u16* t_ = bD + (d_ * 2 + ((h) - 2)) * 8192;                        \
            GLD16(s_, t_);                                                     \
            GLD16(s_ + (size_t)64 * K, t_ + 4096);                            \
        }                                                                      \
    }

    f32x4 acc[8][4] = {};
    bf16x8 af[8][2], bf[4][2];

#pragma unroll
    for (int h = 0; h < 4; ++h) ST_HALF(0, h);
#pragma unroll
    for (int h = 0; h < 4; ++h) ST_HALF(1, h);
    asm volatile("s_waitcnt vmcnt(8)" ::: "memory");
    __builtin_amdgcn_s_barrier();

#pragma unroll 2
    for (int t = 0; t < NT; ++t) {
        const int d = t & 1;
        const u16* Ab = L + (d * 2 + wm) * 8192;
        const u16* Bb = L + 32768 + (d * 2 + (wn >> 1)) * 8192;
        const bool more = (t + 2 < NT);

        // ---- phase 0: read A m0-3 + B n0-1; MFMA Q0
#pragma unroll
        for (int m = 0; m < 4; ++m) {
            const int R = m * 16 + lr;
            af[m][0] = *(const bf16x8*)(Ab + R * 64 + cx0);
            af[m][1] = *(const bf16x8*)(Ab + R * 64 + cx1);
        }
#pragma unroll
        for (int n = 0; n < 2; ++n) {
            const int S = sS + n * 16 + lr;
            bf[n][0] = *(const bf16x8*)(Bb + S * 64 + cx0);
            bf[n][1] = *(const bf16x8*)(Bb + S * 64 + cx1);
        }
        __builtin_amdgcn_s_barrier();
        __builtin_amdgcn_s_setprio(1);
#pragma unroll
        for (int m = 0; m < 4; ++m)
#pragma unroll
            for (int n = 0; n < 2; ++n) {
                acc[m][n] = MFMA16(af[m][0], bf[n][0], acc[m][n]);
                acc[m][n] = MFMA16(af[m][1], bf[n][1], acc[m][n]);
            }
        __builtin_amdgcn_s_setprio(0);
        __builtin_amdgcn_s_barrier();

        // ---- phase 1: read B n2-3; MFMA Q1
#pragma unroll
        for (int n = 2; n < 4; ++n) {
            const int S = sS + n * 16 + lr;
            bf[n][0] = *(const bf16x8*)(Bb + S * 64 + cx0);
            bf[n][1] = *(const bf16x8*)(Bb + S * 64 + cx1);
        }
        __builtin_amdgcn_s_barrier();
        __builtin_amdgcn_s_setprio(1);
#pragma unroll
        for (int m = 0; m < 4; ++m)
#pragma unroll
            for (int n = 2; n < 4; ++n) {
                acc[m][n] = MFMA16(af[m][0], bf[n][0], acc[m][n]);
                acc[m][n] = MFMA16(af[m][1], bf[n][1], acc[m][n]);
            }
        __builtin_amdgcn_s_setprio(0);
        __builtin_amdgcn_s_barrier();

        // ---- phase 2: read A m4-7; stage B halves of t+2; MFMA Q2
#pragma unroll
        for (int m = 4; m < 8; ++m) {
            const int R = m * 16 + lr;
            af[m][0] = *(const bf16x8*)(Ab + R * 64 + cx0);
            af[m][1] = *(const bf16x8*)(Ab + R * 64 + cx1);
        }
        if (more) { ST_HALF(t + 2, 2); ST_HALF(t + 2, 3); }
        __builtin_amdgcn_s_barrier();
        __builtin_amdgcn_s_setprio(1);
#pragma unroll
        for (int m = 4; m < 8; ++m)
#pragma unroll
            for (int n = 0; n < 2; ++n) {
                acc[m][n] = MFMA16(af[m][0], bf[n][0], acc[m][n]);
                acc[m][n] = MFMA16(af[m][1], bf[n][1], acc[m][n]);
            }
        __builtin_amdgcn_s_setprio(0);
        __builtin_amdgcn_s_barrier();

        // ---- phase 3: stage A halves of t+2; MFMA Q3; counted vmcnt
        if (more) { ST_HALF(t + 2, 0); ST_HALF(t + 2, 1); }
        __builtin_amdgcn_s_barrier();
        __builtin_amdgcn_s_setprio(1);
#pragma unroll
        for (int m = 4; m < 8; ++m)
#pragma unroll
            for (int n = 2; n < 4; ++n) {
                acc[m][n] = MFMA16(af[m][0], bf[n][0], acc[m][n]);
                acc[m][n] = MFMA16(af[m][1], bf[n][1], acc[m][n]);
            }
        __builtin_amdgcn_s_setprio(0);
        if (more) asm volatile("s_waitcnt vmcnt(8)" ::: "memory");
        else      asm volatile("s_waitcnt vmcnt(0)" ::: "memory");
        __builtin_amdgcn_s_barrier();
    }
#undef ST_HALF

    const int cr = (lane >> 4) * 4;
    const int cc = lane & 15;
    if constexpr (MODE == 0) {
#pragma unroll
        for (int mf = 0; mf < 8; ++mf)
#pragma unroll
            for (int nf = 0; nf < 4; ++nf) {
                int col = n0 + wn * 64 + nf * 16 + cc;
#pragma unroll
                for (int j = 0; j < 4; ++j) {
                    int row = m0 + wm * 128 + mf * 16 + cr + j;
                    C[(size_t)row * ncols + col] = f2bs(acc[mf][nf][j]);
                }
            }
    } else {
#pragma unroll
        for (int mf = 0; mf < 8; ++mf)
#pragma unroll
            for (int nf = 0; nf < 4; ++nf) {
                int col = n0 + wn * 64 + nf * 16 + cc;
                float bsv = 2.0f * bias[col];
#pragma unroll
                for (int j = 0; j < 4; ++j) {
                    int row = m0 + wm * 128 + mf * 16 + cr + j;
                    out[(size_t)row * ncols + col] = acc[mf][nf][j] + bsv;
                }
            }
    }
}

// ---------- scores + Z: s_st=(x_s.G_t+u.x_s+v.x_t+c)/32 -> softmax ->
//            Z[b] = w0*x[2b] + w1*x[2b+1]  (bf16, vector NT store) ----------
__global__ __launch_bounds__(256) void scores_z(const u16* __restrict__ X,
                                                const u16* __restrict__ G,
                                                const float* __restrict__ u,
                                                const float* __restrict__ v,
                                                const float* __restrict__ cbuf,
                                                u16* __restrict__ Z) {
    const int wave = threadIdx.x >> 6;
    const int lane = threadIdx.x & 63;
    const size_t b = (size_t)blockIdx.x * 4 + wave;
    const u16* x0p = X + (2 * b) * D_DIM;
    const u16* x1p = x0p + D_DIM;
    const u16* g0p = G + (2 * b) * D_DIM;
    const u16* g1p = g0p + D_DIM;

    float d00 = 0.f, d01 = 0.f, d10 = 0.f, d11 = 0.f;
    float au0 = 0.f, au1 = 0.f, bv0 = 0.f, bv1 = 0.f;
    uint4 x0c[2], x1c[2];
#pragma unroll
    for (int s = 0; s < 2; ++s) {
        const int c = s * 512 + lane * 8;
        x0c[s] = *(const uint4*)(x0p + c);
        x1c[s] = *(const uint4*)(x1p + c);
        uint4 g0 = *(const uint4*)(g0p + c);
        uint4 g1 = *(const uint4*)(g1p + c);
        float4 uuA = *(const float4*)(u + c);
        float4 uuB = *(const float4*)(u + c + 4);
        float4 vvA = *(const float4*)(v + c);
        float4 vvB = *(const float4*)(v + c + 4);
        float uA[8] = {uuA.x, uuA.y, uuA.z, uuA.w, uuB.x, uuB.y, uuB.z, uuB.w};
        float vA[8] = {vvA.x, vvA.y, vvA.z, vvA.w, vvB.x, vvB.y, vvB.z, vvB.w};
#pragma unroll
        for (int e = 0; e < 8; ++e) {
            float a0 = b8x(x0c[s], e), a1 = b8x(x1c[s], e);
            float c0 = b8x(g0, e),     c1 = b8x(g1, e);
            d00 = fmaf(a0, c0, d00); d01 = fmaf(a0, c1, d01);
            d10 = fmaf(a1, c0, d10); d11 = fmaf(a1, c1, d11);
            au0 = fmaf(uA[e], a0, au0); au1 = fmaf(uA[e], a1, au1);
            bv0 = fmaf(vA[e], a0, bv0); bv1 = fmaf(vA[e], a1, bv1);
        }
    }
#pragma unroll
    for (int off = 32; off; off >>= 1) {
        d00 += __shfl_xor(d00, off); d01 += __shfl_xor(d01, off);
        d10 += __shfl_xor(d10, off); d11 += __shfl_xor(d11, off);
        au0 += __shfl_xor(au0, off); au1 += __shfl_xor(au1, off);
        bv0 += __shfl_xor(bv0, off); bv1 += __shfl_xor(bv1, off);
    }
    // all lanes hold full sums after the butterfly
    const float cc0 = cbuf[0];
    const float sc = 1.0f / 32.0f;
    float s00 = (d00 + au0 + bv0 + cc0) * sc;
    float s01 = (d01 + au0 + bv1 + cc0) * sc;
    float s10 = (d10 + au1 + bv0 + cc0) * sc;
    float s11 = (d11 + au1 + bv1 + cc0) * sc;
    float mA = fmaxf(s00, s01);
    float e00 = expf(s00 - mA), e01 = expf(s01 - mA);
    float rA = 1.0f / (e00 + e01);
    float mB = fmaxf(s10, s11);
    float e10 = expf(s10 - mB), e11 = expf(s11 - mB);
    float rB = 1.0f / (e10 + e11);
    const float w0 = e00 * rA + e10 * rB;   // weight on row 2b
    const float w1 = e01 * rA + e11 * rB;   // weight on row 2b+1

#pragma unroll
    for (int s = 0; s < 2; ++s) {
        const int c = s * 512 + lane * 8;
        float4 lo, hi;
        lo.x = w0 * b8x(x0c[s], 0) + w1 * b8x(x1c[s], 0);
        lo.y = w0 * b8x(x0c[s], 1) + w1 * b8x(x1c[s], 1);
        lo.z = w0 * b8x(x0c[s], 2) + w1 * b8x(x1c[s], 2);
        lo.w = w0 * b8x(x0c[s], 3) + w1 * b8x(x1c[s], 3);
        hi.x = w0 * b8x(x0c[s], 4) + w1 * b8x(x1c[s], 4);
        hi.y = w0 * b8x(x0c[s], 5) + w1 * b8x(x1c[s], 5);
        hi.z = w0 * b8x(x0c[s], 6) + w1 * b8x(x1c[s], 6);
        hi.w = w0 * b8x(x0c[s], 7) + w1 * b8x(x1c[s], 7);
        uint2 pl = pack4(lo), ph = pack4(hi);
        u32x4 o;
        o[0] = pl.x; o[1] = pl.y; o[2] = ph.x; o[3] = ph.y;
        __builtin_nontemporal_store(o, (u32x4*)(Z + b * D_DIM + c));
    }
}

extern "C" void kernel_launch(void* const* d_in, const int* in_sizes, int n_in,
                              void* d_out, int out_size, void* d_ws, size_t ws_size,
                              hipStream_t stream) {
    const float* f1 = (const float*)d_in[0];
    const float* f2 = (const float*)d_in[1];
    const float* Wq = (const float*)d_in[2];
    const float* bq = (const float*)d_in[3];
    const float* Wk = (const float*)d_in[4];
    const float* bk = (const float*)d_in[5];
    const float* Wv = (const float*)d_in[6];
    const float* bv = (const float*)d_in[7];
    float* out = (float*)d_out;

    // workspace layout (~170 MB)
    char*   w    = (char*)d_ws;
    u16*    X    = (u16*)w;                                  // [32768,1024] bf16 (64 MB)
    u16*    G    = X + (size_t)M_ROWS * D_DIM;               // [32768,1024] bf16 (64 MB)
    u16*    Z    = G + (size_t)M_ROWS * D_DIM;               // [16384,1024] bf16 (32 MB)
    u16*    Wvb  = Z + (size_t)B_ROWS * D_DIM;               // [1024,1024] bf16 (2 MB)
    u16*    WqT  = Wvb + (size_t)D_DIM * D_DIM;              // [1024,1024] bf16 (2 MB)
    u16*    WkT  = WqT + (size_t)D_DIM * D_DIM;              // [1024,1024] bf16 (2 MB)
    u16*    Mb   = WkT + (size_t)D_DIM * D_DIM;              // [1024,1024] bf16 (2 MB)
    float*  u    = (float*)(Mb + (size_t)D_DIM * D_DIM);     // [1024] f32
    float*  v    = u + D_DIM;                                // [1024] f32
    float*  cbuf = v + D_DIM;                                // [64] f32

    // all preprocessing in one dispatch (jobs independent, read raw inputs only)
    prep_all<<<3104 + 2 * ((B_ROWS * D_DIM / 8) / 256), 256, 0, stream>>>(
        f1, f2, Wq, Wk, Wv, bq, bk, X, WqT, WkT, Wvb, u, v, cbuf);

    // M = Wq^T @ Wk : [1024,1024]
    gemm_small<<<(D_DIM / BM) * (D_DIM / BN), 256, 0, stream>>>(WqT, WkT, Mb, D_DIM);
    // G = X @ M^T : [32768,1024]  (8-phase 256^2, 512 blocks)
    gemm8p<0><<<(M_ROWS / 256) * (D_DIM / 256), 512, 0, stream>>>(
        X, Mb, nullptr, G, nullptr, D_DIM);
    // scores -> combine weights -> Z = w0*x0 + w1*x1
    scores_z<<<B_ROWS / 4, 256, 0, stream>>>(X, G, u, v, cbuf, Z);
    // out = Z @ Wv^T + 2*bv : [16384,1024]  (8-phase, 256 blocks, f32 out)
    gemm8p<1><<<(B_ROWS / 256) * (D_DIM / 256), 512, 0, stream>>>(
        Z, Wvb, bv, nullptr, out, D_DIM);
}